// Round 7
// baseline (320.062 us; speedup 1.0000x reference)
//
#include <hip/hip_runtime.h>
#include <stdint.h>

// Problem constants
#define CIN   256
#define COUT  256
#define HH    56
#define WW    56
#define BB    32
#define HP    58            // padded H
#define WP    58            // padded W
#define KTOT  2304          // CIN*3*3, K order = (kh, kw, ci), ci fastest
#define NPIX  (BB*HH*WW)    // 100352
#define OHW   (HH*WW)       // 3136

// Workspace layout
#define WS_AMAX_OFF   0
#define WS_PART_OFF   256                // 2048 float partial maxima
#define WS_WPACK_OFF  16384
#define WPACK_BYTES   (COUT*KTOT)        // 589824
#define WS_XPAD_OFF   (1<<20)
#define XPAD_BYTES    (BB*HP*WP*CIN)     // 27557888

typedef __attribute__((ext_vector_type(4))) int i32x4;

// ---------------------------------------------------------------- absmax ----
// Per-block partial max -> partial[blockIdx.x]. No same-address atomics.
__global__ void absmax_kernel(const float* __restrict__ x,
                              float* __restrict__ partial, int n4) {
  int tid = blockIdx.x * blockDim.x + threadIdx.x;
  int stride = gridDim.x * blockDim.x;
  const float4* x4 = (const float4*)x;
  float m = 0.0f;
  for (int i = tid; i < n4; i += stride) {
    float4 v = x4[i];
    m = fmaxf(m, fmaxf(fmaxf(fabsf(v.x), fabsf(v.y)),
                       fmaxf(fabsf(v.z), fabsf(v.w))));
  }
#pragma unroll
  for (int off = 32; off >= 1; off >>= 1)
    m = fmaxf(m, __shfl_xor(m, off, 64));
  __shared__ float red[4];
  int lane = threadIdx.x & 63, wv = threadIdx.x >> 6;
  if (lane == 0) red[wv] = m;
  __syncthreads();
  if (threadIdx.x == 0)
    partial[blockIdx.x] = fmaxf(fmaxf(red[0], red[1]), fmaxf(red[2], red[3]));
}

// ------------------------------------------- weight pack + amax finalize ----
// wq: [cout][ci][kh][kw] int32 -> wp: [cout][kh][kw][ci] int8.
// Block 0 additionally reduces the 2048 partials into *amax.
__global__ void wpack_kernel(const int* __restrict__ wq, int8_t* __restrict__ wp,
                             const float* __restrict__ partial,
                             unsigned int* __restrict__ amax) {
  if (blockIdx.x == 0) {
    float m = 0.0f;
    for (int i = threadIdx.x; i < 2048; i += 256) m = fmaxf(m, partial[i]);
#pragma unroll
    for (int off = 32; off >= 1; off >>= 1)
      m = fmaxf(m, __shfl_xor(m, off, 64));
    __shared__ float red[4];
    int lane = threadIdx.x & 63, wvv = threadIdx.x >> 6;
    if (lane == 0) red[wvv] = m;
    __syncthreads();
    if (threadIdx.x == 0)
      *amax = __float_as_uint(fmaxf(fmaxf(red[0], red[1]), fmaxf(red[2], red[3])));
  }
  int i = blockIdx.x * 256 + threadIdx.x;   // grid covers 589824 exactly
  int ci   = i & 255;
  int t    = i >> 8;
  int khkw = t % 9;
  int co   = t / 9;
  wp[i] = (int8_t)wq[(co * CIN + ci) * 9 + khkw];
}

// ------------------------------------------------------------- halo zero ----
// Zero only the pad ring of xpad: rows 0 and 57, cols 0 and 57. 16B stores.
__global__ void halo_kernel(int8_t* __restrict__ xpad) {
  int idx = blockIdx.x * 256 + threadIdx.x;   // 456*256 = 116736 exact
  int b = idx / 3648;
  int r = idx - b * 3648;
  long byteoff;
  if (r < 1856) {
    int row = (r < 928) ? 0 : 57;
    int c   = (r < 928) ? r : r - 928;        // 0..927 = 58*16 chunks
    byteoff = ((long)(b * HP + row) * WP) * 256 + (long)c * 16;
  } else {
    int rc = r - 1856;                         // 0..1791
    int h  = (rc >> 5) + 1;                    // 1..56
    int t  = rc & 31;
    int w  = (t < 16) ? 0 : 57;
    int c16 = t & 15;
    byteoff = ((long)((b * HP + h) * WP + w)) * 256 + (long)c16 * 16;
  }
  *(int4*)(xpad + byteoff) = int4{0, 0, 0, 0};
}

// -------------------------------------------------- quantize + pad + NHWC ----
__global__ void quant_kernel(const float* __restrict__ x,
                             const unsigned int* __restrict__ amax,
                             int8_t* __restrict__ xpad) {
  const int cb = blockIdx.x;   // 0..3
  const int h  = blockIdx.y;   // 0..55
  const int b  = blockIdx.z;   // 0..31
  const int ci0 = cb * 64;
  const float xs = __uint_as_float(*amax) / 127.0f;
  __shared__ __align__(16) int8_t t[56 * 68];
  const int tid = threadIdx.x;
  for (int e = tid; e < 64 * 56; e += 256) {
    int ci = e / 56;
    int w  = e - ci * 56;
    float v = x[(((b * CIN) + ci0 + ci) * HH + h) * WW + w];
    float q = rintf(v / xs);
    q = fminf(127.0f, fmaxf(-127.0f, q));
    t[w * 68 + ci] = (int8_t)(int)q;
  }
  __syncthreads();
  uint8_t* dst = (uint8_t*)xpad;
  for (int e = tid; e < 56 * 16; e += 256) {
    int w = e >> 4, c4 = e & 15;
    unsigned int v = *(const unsigned int*)&t[w * 68 + c4 * 4];
    *(unsigned int*)(dst + ((((b * HP) + h + 1) * WP + (w + 1)) << 8) + ci0 + c4 * 4) = v;
  }
}

// ------------------------------------------------------------------- conv ----
// Implicit GEMM, 128x128 tile, BK=64, 36 K-tiles. Ring-3 LDS buffers,
// prefetch distance 2, counted s_waitcnt vmcnt(4) + raw s_barrier (1/K-tile).
__global__ __launch_bounds__(256, 3)
void conv_kernel(const int8_t* __restrict__ xpad, const int8_t* __restrict__ wp,
                 const unsigned int* __restrict__ amax,
                 const float* __restrict__ wscale,
                 const float* __restrict__ bias, float* __restrict__ out) {
  __shared__ __align__(16) int8_t As[3][128 * 64];   // 24 KB
  __shared__ __align__(16) int8_t Bs[3][128 * 64];   // 24 KB

  const int tid  = threadIdx.x;
  const int lane = tid & 63;
  const int wv   = tid >> 6;
  const int wm   = wv >> 1;
  const int wn   = wv & 1;

  // bijective XCD swizzle (grid 1568 % 8 == 0)
  int bx = blockIdx.x;
  const int cpx = gridDim.x >> 3;
  bx = (bx & 7) * cpx + (bx >> 3);
  const int m0 = (bx & 1) << 7;
  const int n0 = (bx >> 1) << 7;

  // Per-thread staging sources with inverse seg-swizzle (rule 21).
  const int8_t* gA[2];
  const int8_t* gB[2];
#pragma unroll
  for (int i = 0; i < 2; ++i) {
    int s = i * 256 + tid;
    int r = s >> 2;
    int slog = (s & 3) ^ ((r >> 1) & 3);
    gA[i] = wp + (m0 + r) * KTOT + slog * 16;
    int p  = n0 + r;
    int ow = p % 56;
    int t1 = p / 56;
    int oh = t1 % 56;
    int b  = t1 / 56;
    gB[i] = xpad + (((b * HP + oh) * WP) + ow) * 256 + slog * 16;
  }

  const int rr = lane & 15;
  const int physseg = ((lane >> 4) ^ ((rr >> 1) & 3)) << 4;

  auto stage = [&](int bsel, int kk) {
    int khkw = kk >> 2;
    int kh = khkw / 3;
    int kw = khkw - kh * 3;
    int koffB = ((kh * WP + kw) << 8) + ((kk & 3) << 6);
    int koffA = kk << 6;
#pragma unroll
    for (int i = 0; i < 2; ++i) {
      __builtin_amdgcn_global_load_lds(
          (const __attribute__((address_space(1))) void*)(gA[i] + koffA),
          (__attribute__((address_space(3))) void*)&As[bsel][i * 4096 + wv * 1024],
          16, 0, 0);
      __builtin_amdgcn_global_load_lds(
          (const __attribute__((address_space(1))) void*)(gB[i] + koffB),
          (__attribute__((address_space(3))) void*)&Bs[bsel][i * 4096 + wv * 1024],
          16, 0, 0);
    }
  };

  i32x4 acc[4][4] = {};

  // Prologue: stage K-tiles 0 and 1 (8 loads/thread), wait for tile 0.
  stage(0, 0);
  stage(1, 1);
  asm volatile("s_waitcnt vmcnt(4)" ::: "memory");
  __builtin_amdgcn_s_barrier();
  __builtin_amdgcn_sched_barrier(0);

  int cur = 0, stg = 2;
  for (int kt = 0; kt < 36; ++kt) {
    if (kt < 34) stage(stg, kt + 2);   // outstanding: (kt+1)'s 4 + these 4

    const int8_t* Ab = As[cur];
    const int8_t* Bb = Bs[cur];
    i32x4 a[4], b[4];
#pragma unroll
    for (int mi = 0; mi < 4; ++mi)
      a[mi] = *(const i32x4*)(Ab + (((wm << 6) + (mi << 4) + rr) << 6) + physseg);
#pragma unroll
    for (int ni = 0; ni < 4; ++ni)
      b[ni] = *(const i32x4*)(Bb + (((wn << 6) + (ni << 4) + rr) << 6) + physseg);
#pragma unroll
    for (int mi = 0; mi < 4; ++mi)
#pragma unroll
      for (int ni = 0; ni < 4; ++ni)
        acc[mi][ni] = __builtin_amdgcn_mfma_i32_16x16x64_i8(a[mi], b[ni], acc[mi][ni], 0, 0, 0);

    // K-tile boundary: wait (counted) for next tile's loads, then barrier.
    if (kt < 34)       asm volatile("s_waitcnt vmcnt(4)" ::: "memory");
    else if (kt == 34) asm volatile("s_waitcnt vmcnt(0)" ::: "memory");
    if (kt < 35) {
      __builtin_amdgcn_s_barrier();
      __builtin_amdgcn_sched_barrier(0);
    }
    cur = (cur == 2) ? 0 : cur + 1;
    stg = (stg == 2) ? 0 : stg + 1;
  }

  // Epilogue: C/D map: row(cout) = (lane>>4)*4 + reg, col(pix) = lane&15
  const float xs = __uint_as_float(*amax) / 127.0f;
  const float cmul = xs * wscale[0];
#pragma unroll
  for (int ni = 0; ni < 4; ++ni) {
    int p  = n0 + (wn << 6) + (ni << 4) + rr;
    int ow = p % 56;
    int t1 = p / 56;
    int oh = t1 % 56;
    int b  = t1 / 56;
    int obase = b * (COUT * OHW) + oh * 56 + ow;
#pragma unroll
    for (int mi = 0; mi < 4; ++mi) {
      int co = m0 + (wm << 6) + (mi << 4) + ((lane >> 4) << 2);
#pragma unroll
      for (int j = 0; j < 4; ++j) {
        out[obase + (co + j) * OHW] = (float)acc[mi][ni][j] * cmul + bias[co + j];
      }
    }
  }
}

// ------------------------------------------------------------------ launch ----
extern "C" void kernel_launch(void* const* d_in, const int* in_sizes, int n_in,
                              void* d_out, int out_size, void* d_ws, size_t ws_size,
                              hipStream_t stream) {
  const float* x       = (const float*)d_in[0];
  const int*   wq      = (const int*)d_in[1];
  const float* wscale  = (const float*)d_in[2];
  const float* bias    = (const float*)d_in[3];
  float* out = (float*)d_out;

  uint8_t* ws = (uint8_t*)d_ws;
  unsigned int* amax = (unsigned int*)(ws + WS_AMAX_OFF);
  float* partial     = (float*)(ws + WS_PART_OFF);
  int8_t* wp   = (int8_t*)(ws + WS_WPACK_OFF);
  int8_t* xpad = (int8_t*)(ws + WS_XPAD_OFF);

  absmax_kernel<<<2048, 256, 0, stream>>>(x, partial, (NPIX * CIN) / 4);
  wpack_kernel<<<WPACK_BYTES / 256, 256, 0, stream>>>(wq, wp, partial, amax);
  halo_kernel<<<456, 256, 0, stream>>>(xpad);
  quant_kernel<<<dim3(4, 56, 32), 256, 0, stream>>>(x, amax, xpad);
  conv_kernel<<<(NPIX / 128) * (COUT / 128), 256, 0, stream>>>(xpad, wp, amax, wscale, bias, out);
}

// Round 8
// 305.942 us; speedup vs baseline: 1.0462x; 1.0462x over previous
//
#include <hip/hip_runtime.h>
#include <stdint.h>

// Problem constants
#define CIN   256
#define COUT  256
#define HH    56
#define WW    56
#define BB    32
#define HP    58            // padded H
#define WP    58            // padded W
#define KTOT  2304          // CIN*3*3, K order = (kh, kw, ci), ci fastest
#define NPIX  (BB*HH*WW)    // 100352
#define OHW   (HH*WW)       // 3136

// Workspace layout
#define WS_AMAX_OFF   0
#define WS_PART_OFF   256                // 2048 float partial maxima
#define WS_WPACK_OFF  16384
#define WPACK_BYTES   (COUT*KTOT)        // 589824
#define WS_XPAD_OFF   (1<<20)
#define XPAD_BYTES    (BB*HP*WP*CIN)     // 27557888

typedef __attribute__((ext_vector_type(4))) int i32x4;

// ---------------------------------------------------------------- absmax ----
// Per-block partial max -> partial[blockIdx.x]. No same-address atomics.
__global__ void absmax_kernel(const float* __restrict__ x,
                              float* __restrict__ partial, int n4) {
  int tid = blockIdx.x * blockDim.x + threadIdx.x;
  int stride = gridDim.x * blockDim.x;
  const float4* x4 = (const float4*)x;
  float m = 0.0f;
  for (int i = tid; i < n4; i += stride) {
    float4 v = x4[i];
    m = fmaxf(m, fmaxf(fmaxf(fabsf(v.x), fabsf(v.y)),
                       fmaxf(fabsf(v.z), fabsf(v.w))));
  }
#pragma unroll
  for (int off = 32; off >= 1; off >>= 1)
    m = fmaxf(m, __shfl_xor(m, off, 64));
  __shared__ float red[4];
  int lane = threadIdx.x & 63, wv = threadIdx.x >> 6;
  if (lane == 0) red[wv] = m;
  __syncthreads();
  if (threadIdx.x == 0)
    partial[blockIdx.x] = fmaxf(fmaxf(red[0], red[1]), fmaxf(red[2], red[3]));
}

// ------------------------------------------- weight pack + amax finalize ----
// wq: [cout][ci][kh][kw] int32 -> wp: [cout][kh][kw][ci] int8.
// Block 0 additionally reduces the 2048 partials into *amax.
__global__ void wpack_kernel(const int* __restrict__ wq, int8_t* __restrict__ wp,
                             const float* __restrict__ partial,
                             unsigned int* __restrict__ amax) {
  if (blockIdx.x == 0) {
    float m = 0.0f;
    for (int i = threadIdx.x; i < 2048; i += 256) m = fmaxf(m, partial[i]);
#pragma unroll
    for (int off = 32; off >= 1; off >>= 1)
      m = fmaxf(m, __shfl_xor(m, off, 64));
    __shared__ float red[4];
    int lane = threadIdx.x & 63, wvv = threadIdx.x >> 6;
    if (lane == 0) red[wvv] = m;
    __syncthreads();
    if (threadIdx.x == 0)
      *amax = __float_as_uint(fmaxf(fmaxf(red[0], red[1]), fmaxf(red[2], red[3])));
  }
  int i = blockIdx.x * 256 + threadIdx.x;   // grid covers 589824 exactly
  int ci   = i & 255;
  int t    = i >> 8;
  int khkw = t % 9;
  int co   = t / 9;
  wp[i] = (int8_t)wq[(co * CIN + ci) * 9 + khkw];
}

// --------------------------------------- quantize + pad + NHWC + halo ----
// x: NCHW fp32 -> xpad: [B][HP][WP][CIN] int8. Halo ring zeroed inline:
// h==0 block zeroes pad row 0, h==55 zeroes pad row 57, every block zeroes
// cols 0 and 57 of its output row h+1. Disjoint writes (per cb ci-range).
__global__ void quant_kernel(const float* __restrict__ x,
                             const unsigned int* __restrict__ amax,
                             int8_t* __restrict__ xpad) {
  const int cb = blockIdx.x;   // 0..3
  const int h  = blockIdx.y;   // 0..55
  const int b  = blockIdx.z;   // 0..31
  const int ci0 = cb * 64;
  const float xs = __uint_as_float(*amax) / 127.0f;
  __shared__ __align__(16) int8_t t[56 * 68];
  const int tid = threadIdx.x;
  uint8_t* dst = (uint8_t*)xpad;

  // fused halo zeroing (16B stores, ci-block slice only)
  const int4 z4 = int4{0, 0, 0, 0};
  if (h == 0) {
    for (int e = tid; e < 58 * 4; e += 256) {
      int w = e >> 2, c = e & 3;
      *(int4*)(dst + (((b * HP + 0) * WP + w) << 8) + ci0 + c * 16) = z4;
    }
  }
  if (h == 55) {
    for (int e = tid; e < 58 * 4; e += 256) {
      int w = e >> 2, c = e & 3;
      *(int4*)(dst + (((b * HP + 57) * WP + w) << 8) + ci0 + c * 16) = z4;
    }
  }
  if (tid < 8) {  // cols 0 and 57 of row h+1
    int w = (tid & 1) ? 57 : 0, c = tid >> 1;
    *(int4*)(dst + (((b * HP + h + 1) * WP + w) << 8) + ci0 + c * 16) = z4;
  }

  for (int e = tid; e < 64 * 56; e += 256) {
    int ci = e / 56;
    int w  = e - ci * 56;
    float v = x[(((b * CIN) + ci0 + ci) * HH + h) * WW + w];
    float q = rintf(v / xs);                         // IEEE div + round-half-even
    q = fminf(127.0f, fmaxf(-127.0f, q));
    t[w * 68 + ci] = (int8_t)(int)q;
  }
  __syncthreads();
  for (int e = tid; e < 56 * 16; e += 256) {
    int w = e >> 4, c4 = e & 15;
    unsigned int v = *(const unsigned int*)&t[w * 68 + c4 * 4];
    *(unsigned int*)(dst + ((((b * HP) + h + 1) * WP + (w + 1)) << 8) + ci0 + c4 * 4) = v;
  }
}

// ------------------------------------------------------------------- conv ----
// Implicit GEMM: A = wp [256 x 2304], B^T = im2col(xpad) [100352 x 2304].
// 128x128 tile, BK=64 (one (kh,kw) ci-quarter per step), 36 K-steps.
// 2-buffer LDS + __syncthreads (R1-measured structure: 94us, MfmaUtil 26%).
__global__ __launch_bounds__(256, 2)
void conv_kernel(const int8_t* __restrict__ xpad, const int8_t* __restrict__ wp,
                 const unsigned int* __restrict__ amax,
                 const float* __restrict__ wscale,
                 const float* __restrict__ bias, float* __restrict__ out) {
  __shared__ __align__(16) int8_t As[2][128 * 64];
  __shared__ __align__(16) int8_t Bs[2][128 * 64];

  const int tid  = threadIdx.x;
  const int lane = tid & 63;
  const int wv   = tid >> 6;       // wave 0..3
  const int wm   = wv >> 1;        // wave row (cout)
  const int wn   = wv & 1;         // wave col (pixel)

  // bijective XCD swizzle (grid 1568 % 8 == 0)
  int bx = blockIdx.x;
  const int cpx = gridDim.x >> 3;
  bx = (bx & 7) * cpx + (bx >> 3);
  const int m0 = (bx & 1) << 7;    // cout tile base
  const int n0 = (bx >> 1) << 7;   // pixel tile base

  // Per-thread staging sources with inverse seg-swizzle (rule 21).
  const int8_t* gA[2];
  const int8_t* gB[2];
#pragma unroll
  for (int i = 0; i < 2; ++i) {
    int s = i * 256 + tid;
    int r = s >> 2;
    int slog = (s & 3) ^ ((r >> 1) & 3);
    gA[i] = wp + (m0 + r) * KTOT + slog * 16;
    int p  = n0 + r;
    int ow = p % 56;
    int t1 = p / 56;
    int oh = t1 % 56;
    int b  = t1 / 56;
    gB[i] = xpad + (((b * HP + oh) * WP) + ow) * 256 + slog * 16;
  }

  const int rr = lane & 15;
  const int physseg = ((lane >> 4) ^ ((rr >> 1) & 3)) << 4;

  auto stage = [&](int bsel, int kk) {
    int khkw = kk >> 2;
    int kh = khkw / 3;
    int kw = khkw - kh * 3;
    int koffB = ((kh * WP + kw) << 8) + ((kk & 3) << 6);
    int koffA = kk << 6;
#pragma unroll
    for (int i = 0; i < 2; ++i) {
      __builtin_amdgcn_global_load_lds(
          (const __attribute__((address_space(1))) void*)(gA[i] + koffA),
          (__attribute__((address_space(3))) void*)&As[bsel][i * 4096 + wv * 1024],
          16, 0, 0);
      __builtin_amdgcn_global_load_lds(
          (const __attribute__((address_space(1))) void*)(gB[i] + koffB),
          (__attribute__((address_space(3))) void*)&Bs[bsel][i * 4096 + wv * 1024],
          16, 0, 0);
    }
  };

  i32x4 acc[4][4] = {};

  stage(0, 0);
  __syncthreads();
  int buf = 0;
  for (int kk = 0; kk < 36; ++kk) {
    if (kk < 35) stage(buf ^ 1, kk + 1);
    const int8_t* Ab = As[buf];
    const int8_t* Bb = Bs[buf];
    i32x4 a[4], b[4];
#pragma unroll
    for (int mi = 0; mi < 4; ++mi)
      a[mi] = *(const i32x4*)(Ab + (((wm << 6) + (mi << 4) + rr) << 6) + physseg);
#pragma unroll
    for (int ni = 0; ni < 4; ++ni)
      b[ni] = *(const i32x4*)(Bb + (((wn << 6) + (ni << 4) + rr) << 6) + physseg);
#pragma unroll
    for (int mi = 0; mi < 4; ++mi)
#pragma unroll
      for (int ni = 0; ni < 4; ++ni)
        acc[mi][ni] = __builtin_amdgcn_mfma_i32_16x16x64_i8(a[mi], b[ni], acc[mi][ni], 0, 0, 0);
    __syncthreads();
    buf ^= 1;
  }

  // Epilogue: C/D map: row(cout) = (lane>>4)*4 + reg, col(pix) = lane&15
  const float xs = __uint_as_float(*amax) / 127.0f;
  const float cmul = xs * wscale[0];
#pragma unroll
  for (int ni = 0; ni < 4; ++ni) {
    int p  = n0 + (wn << 6) + (ni << 4) + rr;
    int ow = p % 56;
    int t1 = p / 56;
    int oh = t1 % 56;
    int b  = t1 / 56;
    int obase = b * (COUT * OHW) + oh * 56 + ow;
#pragma unroll
    for (int mi = 0; mi < 4; ++mi) {
      int co = m0 + (wm << 6) + (mi << 4) + ((lane >> 4) << 2);
#pragma unroll
      for (int j = 0; j < 4; ++j) {
        out[obase + (co + j) * OHW] = (float)acc[mi][ni][j] * cmul + bias[co + j];
      }
    }
  }
}

// ------------------------------------------------------------------ launch ----
extern "C" void kernel_launch(void* const* d_in, const int* in_sizes, int n_in,
                              void* d_out, int out_size, void* d_ws, size_t ws_size,
                              hipStream_t stream) {
  const float* x       = (const float*)d_in[0];
  const int*   wq      = (const int*)d_in[1];
  const float* wscale  = (const float*)d_in[2];
  const float* bias    = (const float*)d_in[3];
  float* out = (float*)d_out;

  uint8_t* ws = (uint8_t*)d_ws;
  unsigned int* amax = (unsigned int*)(ws + WS_AMAX_OFF);
  float* partial     = (float*)(ws + WS_PART_OFF);
  int8_t* wp   = (int8_t*)(ws + WS_WPACK_OFF);
  int8_t* xpad = (int8_t*)(ws + WS_XPAD_OFF);

  absmax_kernel<<<2048, 256, 0, stream>>>(x, partial, (NPIX * CIN) / 4);
  wpack_kernel<<<WPACK_BYTES / 256, 256, 0, stream>>>(wq, wp, partial, amax);
  quant_kernel<<<dim3(4, 56, 32), 256, 0, stream>>>(x, amax, xpad);
  conv_kernel<<<(NPIX / 128) * (COUT / 128), 256, 0, stream>>>(xpad, wp, amax, wscale, bias, out);
}